// Round 1
// baseline (450.282 us; speedup 1.0000x reference)
//
#include <hip/hip_runtime.h>
#include <math.h>

// Problem constants
#define B_    64
#define C_    80
#define DE_   300
#define DE1_  1024
#define J_    4000
#define S_    100
#define KP_   40      // J/S
#define FDIM_ 2048

// Workspace layout (float offsets)
#define WS_FEAT   0          // [64,2048]           131072
#define WS_B1     131072     // [1024,80]            81920
#define WS_B2     212992     // [1024,80]            81920
#define WS_AW     294912     // [80,80]               6400
#define WS_AHAT   301312     // [80,80]               6400
#define WS_T1     307712     // [80,1024]            81920
#define WS_H      389632     // [80,1024]            81920
#define WS_HH     471552     // [80,1024]            81920
#define WS_X      553472     // [80,2048]           163840
#define WS_IMG    717312     // [64,4000]           256000
#define WS_CLS    973312     // [80,4000]           320000
#define WS_POOL   1293312    // [64,80,40]          204800
// total 1498112 floats = 5.99 MB

// ---------------------------------------------------------------- init biases
__global__ void init_kernel(const float* __restrict__ bimg,
                            const float* __restrict__ bcls,
                            const float* __restrict__ bml,
                            float* __restrict__ img, float* __restrict__ cls,
                            float* __restrict__ x, float* __restrict__ out) {
    int idx = blockIdx.x * 256 + threadIdx.x;
    if (idx < 256000) { img[idx] = bimg[idx % 4000]; return; }
    idx -= 256000;
    if (idx < 320000) { cls[idx] = bcls[idx % 4000]; return; }
    idx -= 320000;
    if (idx < 163840) { x[idx] = 0.0f; return; }
    idx -= 163840;
    if (idx < 5120)   { out[idx] = bml[idx % 80]; }
}

// ---------------------------------------------------------------- maxpool 14x14
// one wave per (b,c); 196 floats = 49 float4
__global__ void maxpool_kernel(const float* __restrict__ feature,
                               float* __restrict__ feat) {
    int gtid = blockIdx.x * 256 + threadIdx.x;
    int wid  = gtid >> 6;       // bc index, 0..131071
    int lane = gtid & 63;
    const float* src = feature + (size_t)wid * 196;
    float v = -INFINITY;
    if (lane < 49) {
        float4 u = ((const float4*)src)[lane];
        v = fmaxf(fmaxf(u.x, u.y), fmaxf(u.z, u.w));
    }
    #pragma unroll
    for (int off = 32; off > 0; off >>= 1)
        v = fmaxf(v, __shfl_down(v, off));
    if (lane == 0) feat[wid] = v;
}

// ---------------------------------------------------------------- b1/b2 sigmoid
// b[o][c] = sigmoid(sum_k Wb[o*300+k] * X[k*80+c] + bb[o]);  X = inp flat [300][80]
__global__ void b1b2_kernel(const float* __restrict__ inp,
                            const float* __restrict__ Wb1, const float* __restrict__ bb1,
                            const float* __restrict__ Wb2, const float* __restrict__ bb2,
                            float* __restrict__ b1, float* __restrict__ b2) {
    int idx = blockIdx.x * 256 + threadIdx.x;     // 0 .. 163839
    int which = idx >= 81920;
    int r = which ? idx - 81920 : idx;
    int o = r / 80, c = r % 80;
    const float* W = which ? Wb2 : Wb1;
    const float* bb = which ? bb2 : bb1;
    float acc = bb[o];
    const float* wrow = W + o * 300;
    for (int k = 0; k < 300; ++k)
        acc = fmaf(wrow[k], inp[k * 80 + c], acc);
    float s = 1.0f / (1.0f + expf(-acc));
    (which ? b2 : b1)[r] = s;
}

// ---------------------------------------------------------------- gram: A_wave
// A_wave[i][j] = dot(b1[:,i], b2[:,j]) / 80 + (i==j)
__global__ void gram_kernel(const float* __restrict__ b1,
                            const float* __restrict__ b2,
                            float* __restrict__ Aw) {
    int idx = blockIdx.x * 256 + threadIdx.x;     // 0..6399
    int i = idx / 80, j = idx % 80;
    float acc = 0.f;
    for (int k = 0; k < 1024; ++k)
        acc = fmaf(b1[k * 80 + i], b2[k * 80 + j], acc);
    Aw[idx] = acc * (1.0f / 80.0f) + (i == j ? 1.0f : 0.0f);
}

// ---------------------------------------------------------------- A_hat + loss (1 block)
__global__ void ahat_kernel(const float* __restrict__ Aw,
                            float* __restrict__ Ahat,
                            float* __restrict__ loss_out) {
    __shared__ float dsh[80];
    __shared__ float red[256];
    int tid = threadIdx.x;
    if (tid < 80) {
        float rs = 0.f;
        for (int j = 0; j < 80; ++j) rs += Aw[tid * 80 + j];
        float dv = rsqrtf(rs);
        if (!isfinite(dv)) dv = 0.f;
        dsh[tid] = dv;
    }
    __syncthreads();
    float loss = 0.f;
    for (int idx = tid; idx < 6400; idx += 256) {
        int i = idx / 80, j = idx % 80;
        float ah = dsh[i] * Aw[idx] * dsh[j];
        Ahat[idx] = ah;
        loss += fabsf(ah - (i == j ? 1.0f : 0.0f));
    }
    red[tid] = loss;
    __syncthreads();
    for (int s = 128; s > 0; s >>= 1) {
        if (tid < s) red[tid] += red[tid + s];
        __syncthreads();
    }
    if (tid == 0) *loss_out = red[0];
}

// ---------------------------------------------------------------- t1 = inp @ Wg1  [80,1024]
__global__ void t1_kernel(const float* __restrict__ inp,
                          const float* __restrict__ Wg1,
                          float* __restrict__ t1) {
    int idx = blockIdx.x * 256 + threadIdx.x;     // 0..81919
    int m = idx >> 10, n = idx & 1023;
    float acc = 0.f;
    const float* arow = inp + m * 300;
    for (int k = 0; k < 300; ++k)
        acc = fmaf(arow[k], Wg1[k * 1024 + n], acc);
    t1[idx] = acc;
}

// ---------------------------------------------------------------- h = leaky(Ahat @ t1)
__global__ void h_kernel(const float* __restrict__ Ahat,
                         const float* __restrict__ t1,
                         float* __restrict__ h) {
    int idx = blockIdx.x * 256 + threadIdx.x;
    int m = idx >> 10, n = idx & 1023;
    float acc = 0.f;
    const float* arow = Ahat + m * 80;
    for (int k = 0; k < 80; ++k)
        acc = fmaf(arow[k], t1[k * 1024 + n], acc);
    h[idx] = acc > 0.f ? acc : 0.2f * acc;
}

// ---------------------------------------------------------------- hh = Ahat @ h
__global__ void hh_kernel(const float* __restrict__ Ahat,
                          const float* __restrict__ h,
                          float* __restrict__ hh) {
    int idx = blockIdx.x * 256 + threadIdx.x;
    int m = idx >> 10, n = idx & 1023;
    float acc = 0.f;
    const float* arow = Ahat + m * 80;
    for (int k = 0; k < 80; ++k)
        acc = fmaf(arow[k], h[k * 1024 + n], acc);
    hh[idx] = acc;
}

// ---------------------------------------------------------------- tiled GEMM (split-K, atomic)
// C[M,N] += A[M,K] @ op(B); TRANSB: B is [N,K] (use B^T), else B is [K,N]
template<bool TRANSB>
__device__ __forceinline__ void gemm_tile(const float* __restrict__ A,
                                          const float* __restrict__ B,
                                          float* __restrict__ C,
                                          int M, int N, int K,
                                          int m0, int n0, int k0, int k1) {
    __shared__ float As[16][64];  // [k][m]
    __shared__ float Bs[16][64];  // [k][n]
    const int tid = threadIdx.x;
    const int tx = tid & 15, ty = tid >> 4;
    float acc[4][4] = {};
    for (int kk = k0; kk < k1; kk += 16) {
        {   // A tile: rows m0..m0+63, cols kk..kk+15, stored transposed
            int r = tid >> 2;            // 0..63 (m-local)
            int c4 = (tid & 3) * 4;      // 0,4,8,12 (k-local)
            float4 av = make_float4(0.f, 0.f, 0.f, 0.f);
            if (m0 + r < M) av = *(const float4*)(A + (size_t)(m0 + r) * K + kk + c4);
            As[c4 + 0][r] = av.x; As[c4 + 1][r] = av.y;
            As[c4 + 2][r] = av.z; As[c4 + 3][r] = av.w;
        }
        if (TRANSB) {
            int r = tid >> 2;            // n-local
            int c4 = (tid & 3) * 4;      // k-local
            float4 bv = make_float4(0.f, 0.f, 0.f, 0.f);
            if (n0 + r < N) bv = *(const float4*)(B + (size_t)(n0 + r) * K + kk + c4);
            Bs[c4 + 0][r] = bv.x; Bs[c4 + 1][r] = bv.y;
            Bs[c4 + 2][r] = bv.z; Bs[c4 + 3][r] = bv.w;
        } else {
            int r = tid >> 4;            // k-local 0..15
            int c4 = (tid & 15) * 4;     // n-local
            int col = n0 + c4;
            float4 bv = make_float4(0.f, 0.f, 0.f, 0.f);
            if (col + 3 < N) {
                bv = *(const float4*)(B + (size_t)(kk + r) * N + col);
            } else {
                float tmp[4] = {0.f, 0.f, 0.f, 0.f};
                for (int q = 0; q < 4; ++q)
                    if (col + q < N) tmp[q] = B[(size_t)(kk + r) * N + col + q];
                bv.x = tmp[0]; bv.y = tmp[1]; bv.z = tmp[2]; bv.w = tmp[3];
            }
            *(float4*)&Bs[r][c4] = bv;
        }
        __syncthreads();
        #pragma unroll
        for (int k = 0; k < 16; ++k) {
            float4 a = *(const float4*)&As[k][ty * 4];
            float4 b = *(const float4*)&Bs[k][tx * 4];
            float ar[4] = {a.x, a.y, a.z, a.w};
            float br[4] = {b.x, b.y, b.z, b.w};
            #pragma unroll
            for (int i = 0; i < 4; ++i)
                #pragma unroll
                for (int j = 0; j < 4; ++j)
                    acc[i][j] = fmaf(ar[i], br[j], acc[i][j]);
        }
        __syncthreads();
    }
    #pragma unroll
    for (int i = 0; i < 4; ++i) {
        int row = m0 + ty * 4 + i;
        if (row >= M) continue;
        #pragma unroll
        for (int j = 0; j < 4; ++j) {
            int col = n0 + tx * 4 + j;
            if (col < N) atomicAdd(&C[(size_t)row * N + col], acc[i][j]);
        }
    }
}

// x += hh @ Wg2  : M=80, N=2048, K=1024, split-K 4 (chunk 256)
__global__ void gemm_x_kernel(const float* __restrict__ hh,
                              const float* __restrict__ Wg2,
                              float* __restrict__ x) {
    int n0 = blockIdx.x * 64;
    int m0 = blockIdx.y * 64;
    int k0 = blockIdx.z * 256;
    gemm_tile<false>(hh, Wg2, x, 80, 2048, 1024, m0, n0, k0, k0 + 256);
}

// fused: img += feat @ Wimg^T  (M=64)  and  cls += x @ Wcls^T  (M=80)
// grid: (63 n-tiles, 3 roles, 4 k-chunks of 512)
__global__ void gemm_imgcls_kernel(const float* __restrict__ feat,
                                   const float* __restrict__ Wimg,
                                   const float* __restrict__ x,
                                   const float* __restrict__ Wcls,
                                   float* __restrict__ img,
                                   float* __restrict__ cls) {
    int n0 = blockIdx.x * 64;
    int role = blockIdx.y;
    int k0 = blockIdx.z * 512;
    if (role == 0) {
        gemm_tile<true>(feat, Wimg, img, 64, 4000, 2048, 0, n0, k0, k0 + 512);
    } else {
        gemm_tile<true>(x, Wcls, cls, 80, 4000, 2048, (role - 1) * 64, n0, k0, k0 + 512);
    }
}

// ---------------------------------------------------------------- MFB pooled
// pooled[b][c][k] = sum_s img[b][k*100+s] * cls[c][k*100+s]
__global__ void pool_kernel(const float* __restrict__ img,
                            const float* __restrict__ cls,
                            float* __restrict__ pooled) {
    int idx = blockIdx.x * 256 + threadIdx.x;     // 0..204799
    int b = idx / 3200;
    int rem = idx % 3200;
    int c = rem / 40, k = rem % 40;
    const float4* ia = (const float4*)(img + (size_t)b * 4000 + k * 100);
    const float4* ca = (const float4*)(cls + (size_t)c * 4000 + k * 100);
    float acc = 0.f;
    #pragma unroll 5
    for (int s = 0; s < 25; ++s) {
        float4 u = ia[s], v = ca[s];
        acc = fmaf(u.x, v.x, acc);
        acc = fmaf(u.y, v.y, acc);
        acc = fmaf(u.z, v.z, acc);
        acc = fmaf(u.w, v.w, acc);
    }
    pooled[(size_t)b * 3200 + c * 40 + k] = acc;
}

// ---------------------------------------------------------------- out = pooled @ Wml^T (split-K 4)
__global__ void out_kernel(const float* __restrict__ pooled,
                           const float* __restrict__ Wml,
                           float* __restrict__ out) {
    int idx = blockIdx.x * 256 + threadIdx.x;     // 0..5119 = b*80+co
    int b = idx / 80, co = idx % 80;
    int kb = blockIdx.y * 800;
    const float4* pr = (const float4*)(pooled + (size_t)b * 3200 + kb);
    const float4* wr = (const float4*)(Wml + (size_t)co * 3200 + kb);
    float acc = 0.f;
    for (int k4 = 0; k4 < 200; ++k4) {
        float4 u = pr[k4], v = wr[k4];
        acc = fmaf(u.x, v.x, acc);
        acc = fmaf(u.y, v.y, acc);
        acc = fmaf(u.z, v.z, acc);
        acc = fmaf(u.w, v.w, acc);
    }
    atomicAdd(&out[idx], acc);
}

// ---------------------------------------------------------------- launch
extern "C" void kernel_launch(void* const* d_in, const int* in_sizes, int n_in,
                              void* d_out, int out_size, void* d_ws, size_t ws_size,
                              hipStream_t stream) {
    const float* feature = (const float*)d_in[0];
    const float* inp     = (const float*)d_in[1];
    const float* Wb1     = (const float*)d_in[2];
    const float* bb1     = (const float*)d_in[3];
    const float* Wb2     = (const float*)d_in[4];
    const float* bb2     = (const float*)d_in[5];
    const float* Wg1     = (const float*)d_in[6];
    const float* Wg2     = (const float*)d_in[7];
    const float* Wimg    = (const float*)d_in[8];
    const float* bimg    = (const float*)d_in[9];
    const float* Wcls    = (const float*)d_in[10];
    const float* bcls    = (const float*)d_in[11];
    const float* Wml     = (const float*)d_in[12];
    const float* bml     = (const float*)d_in[13];

    float* ws  = (float*)d_ws;
    float* out = (float*)d_out;            // [64,80] then loss at [5120]

    float* feat   = ws + WS_FEAT;
    float* b1     = ws + WS_B1;
    float* b2     = ws + WS_B2;
    float* Aw     = ws + WS_AW;
    float* Ahat   = ws + WS_AHAT;
    float* t1     = ws + WS_T1;
    float* h      = ws + WS_H;
    float* hh     = ws + WS_HH;
    float* x      = ws + WS_X;
    float* img    = ws + WS_IMG;
    float* cls    = ws + WS_CLS;
    float* pooled = ws + WS_POOL;

    init_kernel<<<2910, 256, 0, stream>>>(bimg, bcls, bml, img, cls, x, out);
    maxpool_kernel<<<32768, 256, 0, stream>>>(feature, feat);
    b1b2_kernel<<<640, 256, 0, stream>>>(inp, Wb1, bb1, Wb2, bb2, b1, b2);
    gram_kernel<<<25, 256, 0, stream>>>(b1, b2, Aw);
    ahat_kernel<<<1, 256, 0, stream>>>(Aw, Ahat, out + 5120);
    t1_kernel<<<320, 256, 0, stream>>>(inp, Wg1, t1);
    h_kernel<<<320, 256, 0, stream>>>(Ahat, t1, h);
    hh_kernel<<<320, 256, 0, stream>>>(Ahat, h, hh);
    gemm_x_kernel<<<dim3(32, 2, 4), 256, 0, stream>>>(hh, Wg2, x);
    gemm_imgcls_kernel<<<dim3(63, 3, 4), 256, 0, stream>>>(feat, Wimg, x, Wcls, img, cls);
    pool_kernel<<<800, 256, 0, stream>>>(img, cls, pooled);
    out_kernel<<<dim3(20, 4), 256, 0, stream>>>(pooled, Wml, out);
}

// Round 2
// 369.791 us; speedup vs baseline: 1.2177x; 1.2177x over previous
//
#include <hip/hip_runtime.h>
#include <math.h>

// Problem constants
#define B_    64
#define C_    80
#define DE_   300
#define DE1_  1024
#define J_    4000
#define S_    100
#define KP_   40      // J/S
#define FDIM_ 2048

// Workspace layout (float offsets)
#define WS_FEAT   0          // [64,2048]           131072
#define WS_B1     131072     // [1024,80]            81920
#define WS_B2     212992     // [1024,80]            81920
#define WS_AW     294912     // [80,80]               6400
#define WS_AHAT   301312     // [80,80]               6400
#define WS_T1     307712     // [80,1024]            81920
#define WS_H      389632     // [80,1024]            81920
#define WS_HH     471552     // [80,1024]            81920
#define WS_X      553472     // [80,2048]           163840
#define WS_IMG    717312     // [64,4000]           256000
#define WS_CLS    973312     // [80,4000]           320000
#define WS_POOL   1293312    // [64,80,40]          204800

typedef __bf16 bf16x8 __attribute__((ext_vector_type(8)));
typedef float  f32x4  __attribute__((ext_vector_type(4)));

__device__ __forceinline__ bf16x8 cvt_bf16x8(float4 a, float4 b) {
    bf16x8 r;
    r[0] = (__bf16)a.x; r[1] = (__bf16)a.y; r[2] = (__bf16)a.z; r[3] = (__bf16)a.w;
    r[4] = (__bf16)b.x; r[5] = (__bf16)b.y; r[6] = (__bf16)b.z; r[7] = (__bf16)b.w;
    return r;
}

// ---------------------------------------------------------------- init: x=0, Aw=I
__global__ void init_kernel(float* __restrict__ x, float* __restrict__ Aw) {
    int idx = blockIdx.x * 256 + threadIdx.x;
    if (idx < 163840) { x[idx] = 0.0f; return; }
    idx -= 163840;
    if (idx < 6400) {
        int i = idx / 80, j = idx % 80;
        Aw[idx] = (i == j) ? 1.0f : 0.0f;
    }
}

// ---------------------------------------------------------------- maxpool 14x14
__global__ void maxpool_kernel(const float* __restrict__ feature,
                               float* __restrict__ feat) {
    int gtid = blockIdx.x * 256 + threadIdx.x;
    int wid  = gtid >> 6;       // bc index, 0..131071
    int lane = gtid & 63;
    const float* src = feature + (size_t)wid * 196;
    float v = -INFINITY;
    if (lane < 49) {
        float4 u = ((const float4*)src)[lane];
        v = fmaxf(fmaxf(u.x, u.y), fmaxf(u.z, u.w));
    }
    #pragma unroll
    for (int off = 32; off > 0; off >>= 1)
        v = fmaxf(v, __shfl_down(v, off));
    if (lane == 0) feat[wid] = v;
}

// ---------------------------------------------------------------- b1/b2 sigmoid
__global__ void b1b2_kernel(const float* __restrict__ inp,
                            const float* __restrict__ Wb1, const float* __restrict__ bb1,
                            const float* __restrict__ Wb2, const float* __restrict__ bb2,
                            float* __restrict__ b1, float* __restrict__ b2) {
    int idx = blockIdx.x * 256 + threadIdx.x;     // 0 .. 163839
    int which = idx >= 81920;
    int r = which ? idx - 81920 : idx;
    int o = r / 80, c = r % 80;
    const float* W = which ? Wb2 : Wb1;
    const float* bb = which ? bb2 : bb1;
    float acc = bb[o];
    const float* wrow = W + o * 300;
    for (int k = 0; k < 300; ++k)
        acc = fmaf(wrow[k], inp[k * 80 + c], acc);
    float s = 1.0f / (1.0f + expf(-acc));
    (which ? b2 : b1)[r] = s;
}

// ---------------------------------------------------------------- gram (split-K 4, atomic)
__global__ void gram_kernel(const float* __restrict__ b1,
                            const float* __restrict__ b2,
                            float* __restrict__ Aw) {
    int idx = blockIdx.x * 256 + threadIdx.x;     // 0..6399
    int i = idx / 80, j = idx % 80;
    int k0 = blockIdx.y * 256;
    float acc = 0.f;
    for (int k = k0; k < k0 + 256; ++k)
        acc = fmaf(b1[k * 80 + i], b2[k * 80 + j], acc);
    atomicAdd(&Aw[idx], acc * (1.0f / 80.0f));
}

// ---------------------------------------------------------------- A_hat + loss (1 block)
__global__ void ahat_kernel(const float* __restrict__ Aw,
                            float* __restrict__ Ahat,
                            float* __restrict__ loss_out) {
    __shared__ float dsh[80];
    __shared__ float red[256];
    int tid = threadIdx.x;
    if (tid < 80) {
        float rs = 0.f;
        for (int j = 0; j < 80; ++j) rs += Aw[tid * 80 + j];
        float dv = rsqrtf(rs);
        if (!isfinite(dv)) dv = 0.f;
        dsh[tid] = dv;
    }
    __syncthreads();
    float loss = 0.f;
    for (int idx = tid; idx < 6400; idx += 256) {
        int i = idx / 80, j = idx % 80;
        float ah = dsh[i] * Aw[idx] * dsh[j];
        Ahat[idx] = ah;
        loss += fabsf(ah - (i == j ? 1.0f : 0.0f));
    }
    red[tid] = loss;
    __syncthreads();
    for (int s = 128; s > 0; s >>= 1) {
        if (tid < s) red[tid] += red[tid + s];
        __syncthreads();
    }
    if (tid == 0) *loss_out = red[0];
}

// ---------------------------------------------------------------- t1 = inp @ Wg1  [80,1024]
__global__ void t1_kernel(const float* __restrict__ inp,
                          const float* __restrict__ Wg1,
                          float* __restrict__ t1) {
    int idx = blockIdx.x * 256 + threadIdx.x;     // 0..81919
    int m = idx >> 10, n = idx & 1023;
    float acc = 0.f;
    const float* arow = inp + m * 300;
    for (int k = 0; k < 300; ++k)
        acc = fmaf(arow[k], Wg1[k * 1024 + n], acc);
    t1[idx] = acc;
}

// ---------------------------------------------------------------- h = leaky(Ahat @ t1)
__global__ void h_kernel(const float* __restrict__ Ahat,
                         const float* __restrict__ t1,
                         float* __restrict__ h) {
    int idx = blockIdx.x * 256 + threadIdx.x;
    int m = idx >> 10, n = idx & 1023;
    float acc = 0.f;
    const float* arow = Ahat + m * 80;
    for (int k = 0; k < 80; ++k)
        acc = fmaf(arow[k], t1[k * 1024 + n], acc);
    h[idx] = acc > 0.f ? acc : 0.2f * acc;
}

// ---------------------------------------------------------------- hh = Ahat @ h
__global__ void hh_kernel(const float* __restrict__ Ahat,
                          const float* __restrict__ h,
                          float* __restrict__ hh) {
    int idx = blockIdx.x * 256 + threadIdx.x;
    int m = idx >> 10, n = idx & 1023;
    float acc = 0.f;
    const float* arow = Ahat + m * 80;
    for (int k = 0; k < 80; ++k)
        acc = fmaf(arow[k], h[k * 1024 + n], acc);
    hh[idx] = acc;
}

// ---------------------------------------------------------------- x += hh @ Wg2 (MFMA bf16, split-K 2)
// M=80 (5 waves x 16 rows), N-tile=32 (2 n-frags), K-chunk=512
__global__ __launch_bounds__(320) void gemm_x_mfma(const float* __restrict__ hh,
                                                   const float* __restrict__ Wg2,
                                                   float* __restrict__ x) {
    int w = threadIdx.x >> 6;
    int lane = threadIdx.x & 63;
    int r = lane & 15, q = lane >> 4;
    int n0 = blockIdx.x * 32;
    int k0base = blockIdx.y * 512;
    int m0 = w * 16;

    const float* arow = hh + (size_t)(m0 + r) * 1024 + k0base + q * 8;
    const float* bcol = Wg2 + (size_t)(k0base + q * 8) * 2048 + n0 + r;

    f32x4 acc0 = {0.f, 0.f, 0.f, 0.f}, acc1 = {0.f, 0.f, 0.f, 0.f};
    for (int ks = 0; ks < 16; ++ks) {
        float4 a0 = *(const float4*)(arow + ks * 32);
        float4 a1 = *(const float4*)(arow + ks * 32 + 4);
        bf16x8 afrag = cvt_bf16x8(a0, a1);
        const float* bp = bcol + (size_t)ks * 32 * 2048;
        bf16x8 bf0, bf1;
        #pragma unroll
        for (int j = 0; j < 8; ++j) {
            bf0[j] = (__bf16)bp[(size_t)j * 2048];
            bf1[j] = (__bf16)bp[(size_t)j * 2048 + 16];
        }
        acc0 = __builtin_amdgcn_mfma_f32_16x16x32_bf16(afrag, bf0, acc0, 0, 0, 0);
        acc1 = __builtin_amdgcn_mfma_f32_16x16x32_bf16(afrag, bf1, acc1, 0, 0, 0);
    }
    #pragma unroll
    for (int i = 0; i < 4; ++i) {
        int row = m0 + q * 4 + i;
        atomicAdd(&x[(size_t)row * 2048 + n0 + r], acc0[i]);
        atomicAdd(&x[(size_t)row * 2048 + n0 + 16 + r], acc1[i]);
    }
}

// ---------------------------------------------------------------- img/cls GEMM (MFMA bf16)
// role 0: img = feat @ Wimg^T + bimg  (M=64, 4 waves)
// role 1: cls = x @ Wcls^T + bcls     (M=80, 5 waves)
// N-tile=32 (125 tiles, exact), K=2048 full per block. Bias fused into store.
__global__ __launch_bounds__(320) void gemm_imgcls_mfma(
        const float* __restrict__ feat, const float* __restrict__ Wimg,
        const float* __restrict__ bimg,
        const float* __restrict__ x, const float* __restrict__ Wcls,
        const float* __restrict__ bcls,
        float* __restrict__ img, float* __restrict__ cls) {
    int role = blockIdx.y;
    int w = threadIdx.x >> 6;
    if (role == 0 && w >= 4) return;
    int lane = threadIdx.x & 63;
    int r = lane & 15, q = lane >> 4;
    int n0 = blockIdx.x * 32;
    int m0 = w * 16;

    const float* A    = role ? x    : feat;
    const float* W    = role ? Wcls : Wimg;
    const float* bias = role ? bcls : bimg;
    float* Cout       = role ? cls  : img;

    const float4* arow = (const float4*)(A + (size_t)(m0 + r) * 2048 + q * 8);
    const float4* b0row = (const float4*)(W + (size_t)(n0 + r) * 2048 + q * 8);
    const float4* b1row = (const float4*)(W + (size_t)(n0 + 16 + r) * 2048 + q * 8);

    f32x4 acc0 = {0.f, 0.f, 0.f, 0.f}, acc1 = {0.f, 0.f, 0.f, 0.f};
    for (int ks = 0; ks < 64; ++ks) {
        float4 a0 = arow[ks * 8], a1 = arow[ks * 8 + 1];
        float4 b00 = b0row[ks * 8], b01 = b0row[ks * 8 + 1];
        float4 b10 = b1row[ks * 8], b11 = b1row[ks * 8 + 1];
        bf16x8 afrag = cvt_bf16x8(a0, a1);
        bf16x8 bf0 = cvt_bf16x8(b00, b01);
        bf16x8 bf1 = cvt_bf16x8(b10, b11);
        acc0 = __builtin_amdgcn_mfma_f32_16x16x32_bf16(afrag, bf0, acc0, 0, 0, 0);
        acc1 = __builtin_amdgcn_mfma_f32_16x16x32_bf16(afrag, bf1, acc1, 0, 0, 0);
    }
    float bia0 = bias[n0 + r];
    float bia1 = bias[n0 + 16 + r];
    #pragma unroll
    for (int i = 0; i < 4; ++i) {
        int row = m0 + q * 4 + i;
        Cout[(size_t)row * 4000 + n0 + r]      = acc0[i] + bia0;
        Cout[(size_t)row * 4000 + n0 + 16 + r] = acc1[i] + bia1;
    }
}

// ---------------------------------------------------------------- MFB pooled
__global__ void pool_kernel(const float* __restrict__ img,
                            const float* __restrict__ cls,
                            float* __restrict__ pooled) {
    int idx = blockIdx.x * 256 + threadIdx.x;     // 0..204799
    int b = idx / 3200;
    int rem = idx % 3200;
    int c = rem / 40, k = rem % 40;
    const float4* ia = (const float4*)(img + (size_t)b * 4000 + k * 100);
    const float4* ca = (const float4*)(cls + (size_t)c * 4000 + k * 100);
    float acc = 0.f;
    #pragma unroll 5
    for (int s = 0; s < 25; ++s) {
        float4 u = ia[s], v = ca[s];
        acc = fmaf(u.x, v.x, acc);
        acc = fmaf(u.y, v.y, acc);
        acc = fmaf(u.z, v.z, acc);
        acc = fmaf(u.w, v.w, acc);
    }
    pooled[(size_t)b * 3200 + c * 40 + k] = acc;
}

// ---------------------------------------------------------------- out: one wave per output
__global__ void out_kernel(const float* __restrict__ pooled,
                           const float* __restrict__ Wml,
                           const float* __restrict__ bml,
                           float* __restrict__ out) {
    int gid = blockIdx.x * 256 + threadIdx.x;
    int wid = gid >> 6;       // 0..5119
    int lane = gid & 63;
    int b = wid / 80, co = wid % 80;
    const float* pr = pooled + (size_t)b * 3200;
    const float* wr = Wml + (size_t)co * 3200;
    float acc = 0.f;
    for (int k = lane; k < 3200; k += 64)
        acc = fmaf(pr[k], wr[k], acc);
    #pragma unroll
    for (int off = 32; off > 0; off >>= 1)
        acc += __shfl_down(acc, off);
    if (lane == 0) out[wid] = acc + bml[co];
}

// ---------------------------------------------------------------- launch
extern "C" void kernel_launch(void* const* d_in, const int* in_sizes, int n_in,
                              void* d_out, int out_size, void* d_ws, size_t ws_size,
                              hipStream_t stream) {
    const float* feature = (const float*)d_in[0];
    const float* inp     = (const float*)d_in[1];
    const float* Wb1     = (const float*)d_in[2];
    const float* bb1     = (const float*)d_in[3];
    const float* Wb2     = (const float*)d_in[4];
    const float* bb2     = (const float*)d_in[5];
    const float* Wg1     = (const float*)d_in[6];
    const float* Wg2     = (const float*)d_in[7];
    const float* Wimg    = (const float*)d_in[8];
    const float* bimg    = (const float*)d_in[9];
    const float* Wcls    = (const float*)d_in[10];
    const float* bcls    = (const float*)d_in[11];
    const float* Wml     = (const float*)d_in[12];
    const float* bml     = (const float*)d_in[13];

    float* ws  = (float*)d_ws;
    float* out = (float*)d_out;            // [64,80] then loss at [5120]

    float* feat   = ws + WS_FEAT;
    float* b1     = ws + WS_B1;
    float* b2     = ws + WS_B2;
    float* Aw     = ws + WS_AW;
    float* Ahat   = ws + WS_AHAT;
    float* t1     = ws + WS_T1;
    float* h      = ws + WS_H;
    float* hh     = ws + WS_HH;
    float* x      = ws + WS_X;
    float* img    = ws + WS_IMG;
    float* cls    = ws + WS_CLS;
    float* pooled = ws + WS_POOL;

    init_kernel<<<666, 256, 0, stream>>>(x, Aw);
    maxpool_kernel<<<32768, 256, 0, stream>>>(feature, feat);
    b1b2_kernel<<<640, 256, 0, stream>>>(inp, Wb1, bb1, Wb2, bb2, b1, b2);
    gram_kernel<<<dim3(25, 4), 256, 0, stream>>>(b1, b2, Aw);
    ahat_kernel<<<1, 256, 0, stream>>>(Aw, Ahat, out + 5120);
    t1_kernel<<<320, 256, 0, stream>>>(inp, Wg1, t1);
    h_kernel<<<320, 256, 0, stream>>>(Ahat, t1, h);
    hh_kernel<<<320, 256, 0, stream>>>(Ahat, h, hh);
    gemm_x_mfma<<<dim3(64, 2), 320, 0, stream>>>(hh, Wg2, x);
    gemm_imgcls_mfma<<<dim3(125, 2), 320, 0, stream>>>(feat, Wimg, bimg, x, Wcls, bcls, img, cls);
    pool_kernel<<<800, 256, 0, stream>>>(img, cls, pooled);
    out_kernel<<<1280, 256, 0, stream>>>(pooled, Wml, bml, out);
}

// Round 3
// 349.317 us; speedup vs baseline: 1.2890x; 1.0586x over previous
//
#include <hip/hip_runtime.h>
#include <math.h>

// Problem constants
#define B_    64
#define C_    80
#define DE_   300
#define DE1_  1024
#define J_    4000
#define S_    100
#define KP_   40      // J/S
#define FDIM_ 2048

// Workspace layout (float offsets)
#define WS_FEAT   0          // [64,2048]           131072
#define WS_B1     131072     // [1024,80]            81920
#define WS_B2     212992     // [1024,80]            81920
#define WS_AW     294912     // [80,80]               6400
#define WS_AHAT   301312     // [80,80]               6400
#define WS_T1     307712     // [80,1024]            81920
#define WS_H      389632     // [80,1024]            81920
#define WS_HH     471552     // [80,1024]            81920
#define WS_X      553472     // [80,2048]           163840
#define WS_IMG    717312     // [64,4000]           256000
#define WS_CLS    973312     // [80,4000]           320000
#define WS_POOL   1293312    // [64,80,40]          204800

typedef __bf16 bf16x8 __attribute__((ext_vector_type(8)));
typedef float  f32x4  __attribute__((ext_vector_type(4)));

__device__ __forceinline__ bf16x8 cvt_bf16x8(float4 a, float4 b) {
    bf16x8 r;
    r[0] = (__bf16)a.x; r[1] = (__bf16)a.y; r[2] = (__bf16)a.z; r[3] = (__bf16)a.w;
    r[4] = (__bf16)b.x; r[5] = (__bf16)b.y; r[6] = (__bf16)b.z; r[7] = (__bf16)b.w;
    return r;
}

// MFMA tile: A row-major [.,K], W row-major [N,K] (B^T). 16 rows x 32 cols,
// KSTEPS k-steps of 32. Pointers pre-offset: A0 = A+(m0+r)*K+k0+q*8, etc.
template<int KSTEPS>
__device__ __forceinline__ void mfma_bt_tile(const float* __restrict__ A0,
                                             const float* __restrict__ B0,
                                             const float* __restrict__ B1,
                                             f32x4& acc0, f32x4& acc1) {
    #pragma unroll 4
    for (int ks = 0; ks < KSTEPS; ++ks) {
        const float4* ap = (const float4*)(A0 + ks * 32);
        const float4* b0 = (const float4*)(B0 + ks * 32);
        const float4* b1 = (const float4*)(B1 + ks * 32);
        float4 a0 = ap[0], a1 = ap[1];
        float4 b00 = b0[0], b01 = b0[1];
        float4 b10 = b1[0], b11 = b1[1];
        bf16x8 af  = cvt_bf16x8(a0, a1);
        bf16x8 bf0 = cvt_bf16x8(b00, b01);
        bf16x8 bf1 = cvt_bf16x8(b10, b11);
        acc0 = __builtin_amdgcn_mfma_f32_16x16x32_bf16(af, bf0, acc0, 0, 0, 0);
        acc1 = __builtin_amdgcn_mfma_f32_16x16x32_bf16(af, bf1, acc1, 0, 0, 0);
    }
}

__device__ __forceinline__ void mfma_store_atomic(float* __restrict__ C, int Nst,
                                                  int m0, int n0, int r, int q,
                                                  const f32x4& acc0, const f32x4& acc1) {
    #pragma unroll
    for (int i = 0; i < 4; ++i) {
        int row = m0 + q * 4 + i;
        atomicAdd(&C[(size_t)row * Nst + n0 + r], acc0[i]);
        atomicAdd(&C[(size_t)row * Nst + n0 + 16 + r], acc1[i]);
    }
}

// ================================================================ launch 1
// blocks [0,32768): maxpool.  blocks [32768,36003): init (x=0,Aw=I,t1=0,img=bimg,cls=bcls)
__global__ void fused_init_maxpool(const float* __restrict__ feature,
                                   float* __restrict__ feat,
                                   float* __restrict__ x, float* __restrict__ Aw,
                                   float* __restrict__ t1,
                                   const float* __restrict__ bimg, float* __restrict__ img,
                                   const float* __restrict__ bcls, float* __restrict__ cls) {
    if (blockIdx.x < 32768) {
        int gtid = blockIdx.x * 256 + threadIdx.x;
        int wid  = gtid >> 6;       // 0..131071
        int lane = gtid & 63;
        const float* src = feature + (size_t)wid * 196;
        float v = -INFINITY;
        if (lane < 49) {
            float4 u = ((const float4*)src)[lane];
            v = fmaxf(fmaxf(u.x, u.y), fmaxf(u.z, u.w));
        }
        #pragma unroll
        for (int off = 32; off > 0; off >>= 1)
            v = fmaxf(v, __shfl_down(v, off));
        if (lane == 0) feat[wid] = v;
        return;
    }
    int idx = (blockIdx.x - 32768) * 256 + threadIdx.x;
    if (idx < 163840) { x[idx] = 0.0f; return; }
    idx -= 163840;
    if (idx < 6400) {
        int i = idx / 80, j = idx % 80;
        Aw[idx] = (i == j) ? 1.0f : 0.0f;
        return;
    }
    idx -= 6400;
    if (idx < 81920) { t1[idx] = 0.0f; return; }
    idx -= 81920;
    if (idx < 256000) { img[idx] = bimg[idx % 4000]; return; }
    idx -= 256000;
    if (idx < 320000) { cls[idx] = bcls[idx % 4000]; }
}

// ================================================================ launch 2
// blocks [0,640): b1b2 | [640,1920): t1 split-K4 | [1920,2420): img MFMA split-K4
__global__ void fused_stage2(const float* __restrict__ inp,
                             const float* __restrict__ Wb1, const float* __restrict__ bb1,
                             const float* __restrict__ Wb2, const float* __restrict__ bb2,
                             float* __restrict__ b1, float* __restrict__ b2,
                             const float* __restrict__ Wg1, float* __restrict__ t1,
                             const float* __restrict__ feat, const float* __restrict__ Wimg,
                             float* __restrict__ img) {
    int bid = blockIdx.x;
    if (bid < 640) {
        // ---- b1/b2 sigmoid
        int idx = bid * 256 + threadIdx.x;     // 0 .. 163839
        int which = idx >= 81920;
        int r = which ? idx - 81920 : idx;
        int o = r / 80, c = r % 80;
        const float* W = which ? Wb2 : Wb1;
        const float* bb = which ? bb2 : bb1;
        float acc = bb[o];
        const float* wrow = W + o * 300;
        #pragma unroll 10
        for (int k = 0; k < 300; ++k)
            acc = fmaf(wrow[k], inp[k * 80 + c], acc);
        float s = 1.0f / (1.0f + expf(-acc));
        (which ? b2 : b1)[r] = s;
        return;
    }
    if (bid < 1920) {
        // ---- t1 += inp @ Wg1 (split-K 4, chunks of 75)
        int bid2 = bid - 640;
        int chunk = bid2 / 320, blk = bid2 % 320;
        int idx = blk * 256 + threadIdx.x;     // 0..81919
        int m = idx >> 10, n = idx & 1023;
        float acc = 0.f;
        const float* arow = inp + m * 300;
        int k0 = chunk * 75;
        #pragma unroll 5
        for (int k = k0; k < k0 + 75; ++k)
            acc = fmaf(arow[k], Wg1[k * 1024 + n], acc);
        atomicAdd(&t1[idx], acc);
        return;
    }
    // ---- img += feat @ Wimg^T (MFMA, split-K 4, 4 waves x 16 rows, n-tile 32)
    int bid3 = bid - 1920;                     // 0..499
    int nt = bid3 % 125, kc = bid3 / 125;
    int w = threadIdx.x >> 6;
    int lane = threadIdx.x & 63;
    int r = lane & 15, q = lane >> 4;
    int n0 = nt * 32, m0 = w * 16, k0 = kc * 512;
    const float* A0 = feat + (size_t)(m0 + r) * 2048 + k0 + q * 8;
    const float* B0 = Wimg + (size_t)(n0 + r) * 2048 + k0 + q * 8;
    const float* B1 = Wimg + (size_t)(n0 + 16 + r) * 2048 + k0 + q * 8;
    f32x4 acc0 = {0.f, 0.f, 0.f, 0.f}, acc1 = {0.f, 0.f, 0.f, 0.f};
    mfma_bt_tile<16>(A0, B0, B1, acc0, acc1);
    mfma_store_atomic(img, 4000, m0, n0, r, q, acc0, acc1);
}

// ---------------------------------------------------------------- gram (split-K 8)
__global__ void gram_kernel(const float* __restrict__ b1,
                            const float* __restrict__ b2,
                            float* __restrict__ Aw) {
    int idx = blockIdx.x * 256 + threadIdx.x;     // 0..6399
    int i = idx / 80, j = idx % 80;
    int k0 = blockIdx.y * 128;
    float acc = 0.f;
    #pragma unroll 8
    for (int k = k0; k < k0 + 128; ++k)
        acc = fmaf(b1[k * 80 + i], b2[k * 80 + j], acc);
    atomicAdd(&Aw[idx], acc * (1.0f / 80.0f));
}

// ---------------------------------------------------------------- A_hat + loss
__global__ void ahat_kernel(const float* __restrict__ Aw,
                            float* __restrict__ Ahat,
                            float* __restrict__ loss_out) {
    __shared__ float dsh[80];
    __shared__ float red[256];
    int tid = threadIdx.x;
    if (tid < 80) {
        float rs = 0.f;
        #pragma unroll 8
        for (int j = 0; j < 80; ++j) rs += Aw[tid * 80 + j];
        float dv = rsqrtf(rs);
        if (!isfinite(dv)) dv = 0.f;
        dsh[tid] = dv;
    }
    __syncthreads();
    float loss = 0.f;
    for (int idx = tid; idx < 6400; idx += 256) {
        int i = idx / 80, j = idx % 80;
        float ah = dsh[i] * Aw[idx] * dsh[j];
        Ahat[idx] = ah;
        loss += fabsf(ah - (i == j ? 1.0f : 0.0f));
    }
    red[tid] = loss;
    __syncthreads();
    for (int s = 128; s > 0; s >>= 1) {
        if (tid < s) red[tid] += red[tid + s];
        __syncthreads();
    }
    if (tid == 0) *loss_out = red[0];
}

// ---------------------------------------------------------------- h = leaky(Ahat @ t1)
__global__ void h_kernel(const float* __restrict__ Ahat,
                         const float* __restrict__ t1,
                         float* __restrict__ h) {
    int idx = blockIdx.x * 256 + threadIdx.x;
    int m = idx >> 10, n = idx & 1023;
    float acc = 0.f;
    const float* arow = Ahat + m * 80;
    #pragma unroll 8
    for (int k = 0; k < 80; ++k)
        acc = fmaf(arow[k], t1[k * 1024 + n], acc);
    h[idx] = acc > 0.f ? acc : 0.2f * acc;
}

// ---------------------------------------------------------------- hh = Ahat @ h
__global__ void hh_kernel(const float* __restrict__ Ahat,
                          const float* __restrict__ h,
                          float* __restrict__ hh) {
    int idx = blockIdx.x * 256 + threadIdx.x;
    int m = idx >> 10, n = idx & 1023;
    float acc = 0.f;
    const float* arow = Ahat + m * 80;
    #pragma unroll 8
    for (int k = 0; k < 80; ++k)
        acc = fmaf(arow[k], h[k * 1024 + n], acc);
    hh[idx] = acc;
}

// ---------------------------------------------------------------- x += hh @ Wg2 (MFMA, split-K 4)
// M=80 (5 waves), N-tile 32 (64 tiles), K-chunk 256 (8 ks)
__global__ __launch_bounds__(320) void gemm_x_mfma(const float* __restrict__ hh,
                                                   const float* __restrict__ Wg2,
                                                   float* __restrict__ x) {
    int w = threadIdx.x >> 6;
    int lane = threadIdx.x & 63;
    int r = lane & 15, q = lane >> 4;
    int n0 = blockIdx.x * 32;
    int k0 = blockIdx.y * 256;
    int m0 = w * 16;

    const float* arow = hh + (size_t)(m0 + r) * 1024 + k0 + q * 8;
    const float* bcol = Wg2 + (size_t)(k0 + q * 8) * 2048 + n0 + r;

    f32x4 acc0 = {0.f, 0.f, 0.f, 0.f}, acc1 = {0.f, 0.f, 0.f, 0.f};
    #pragma unroll 2
    for (int ks = 0; ks < 8; ++ks) {
        float4 a0 = *(const float4*)(arow + ks * 32);
        float4 a1 = *(const float4*)(arow + ks * 32 + 4);
        bf16x8 afrag = cvt_bf16x8(a0, a1);
        const float* bp = bcol + (size_t)ks * 32 * 2048;
        bf16x8 bf0, bf1;
        #pragma unroll
        for (int j = 0; j < 8; ++j) {
            bf0[j] = (__bf16)bp[(size_t)j * 2048];
            bf1[j] = (__bf16)bp[(size_t)j * 2048 + 16];
        }
        acc0 = __builtin_amdgcn_mfma_f32_16x16x32_bf16(afrag, bf0, acc0, 0, 0, 0);
        acc1 = __builtin_amdgcn_mfma_f32_16x16x32_bf16(afrag, bf1, acc1, 0, 0, 0);
    }
    mfma_store_atomic(x, 2048, m0, n0, r, q, acc0, acc1);
}

// ---------------------------------------------------------------- cls += x @ Wcls^T (MFMA, split-K 4)
__global__ __launch_bounds__(320) void gemm_cls_mfma(const float* __restrict__ x,
                                                     const float* __restrict__ Wcls,
                                                     float* __restrict__ cls) {
    int w = threadIdx.x >> 6;
    int lane = threadIdx.x & 63;
    int r = lane & 15, q = lane >> 4;
    int n0 = blockIdx.x * 32;
    int k0 = blockIdx.y * 512;
    int m0 = w * 16;
    const float* A0 = x    + (size_t)(m0 + r) * 2048 + k0 + q * 8;
    const float* B0 = Wcls + (size_t)(n0 + r) * 2048 + k0 + q * 8;
    const float* B1 = Wcls + (size_t)(n0 + 16 + r) * 2048 + k0 + q * 8;
    f32x4 acc0 = {0.f, 0.f, 0.f, 0.f}, acc1 = {0.f, 0.f, 0.f, 0.f};
    mfma_bt_tile<16>(A0, B0, B1, acc0, acc1);
    mfma_store_atomic(cls, 4000, m0, n0, r, q, acc0, acc1);
}

// ---------------------------------------------------------------- MFB pooled
__global__ void pool_kernel(const float* __restrict__ img,
                            const float* __restrict__ cls,
                            float* __restrict__ pooled) {
    int idx = blockIdx.x * 256 + threadIdx.x;     // 0..204799
    int b = idx / 3200;
    int rem = idx % 3200;
    int c = rem / 40, k = rem % 40;
    const float4* ia = (const float4*)(img + (size_t)b * 4000 + k * 100);
    const float4* ca = (const float4*)(cls + (size_t)c * 4000 + k * 100);
    float acc = 0.f;
    #pragma unroll 5
    for (int s = 0; s < 25; ++s) {
        float4 u = ia[s], v = ca[s];
        acc = fmaf(u.x, v.x, acc);
        acc = fmaf(u.y, v.y, acc);
        acc = fmaf(u.z, v.z, acc);
        acc = fmaf(u.w, v.w, acc);
    }
    pooled[(size_t)b * 3200 + c * 40 + k] = acc;
}

// ---------------------------------------------------------------- out: one wave per output
__global__ void out_kernel(const float* __restrict__ pooled,
                           const float* __restrict__ Wml,
                           const float* __restrict__ bml,
                           float* __restrict__ out) {
    int gid = blockIdx.x * 256 + threadIdx.x;
    int wid = gid >> 6;       // 0..5119
    int lane = gid & 63;
    int b = wid / 80, co = wid % 80;
    const float* pr = pooled + (size_t)b * 3200;
    const float* wr = Wml + (size_t)co * 3200;
    float acc = 0.f;
    #pragma unroll 5
    for (int k = lane; k < 3200; k += 64)
        acc = fmaf(pr[k], wr[k], acc);
    #pragma unroll
    for (int off = 32; off > 0; off >>= 1)
        acc += __shfl_down(acc, off);
    if (lane == 0) out[wid] = acc + bml[co];
}

// ---------------------------------------------------------------- launch
extern "C" void kernel_launch(void* const* d_in, const int* in_sizes, int n_in,
                              void* d_out, int out_size, void* d_ws, size_t ws_size,
                              hipStream_t stream) {
    const float* feature = (const float*)d_in[0];
    const float* inp     = (const float*)d_in[1];
    const float* Wb1     = (const float*)d_in[2];
    const float* bb1     = (const float*)d_in[3];
    const float* Wb2     = (const float*)d_in[4];
    const float* bb2     = (const float*)d_in[5];
    const float* Wg1     = (const float*)d_in[6];
    const float* Wg2     = (const float*)d_in[7];
    const float* Wimg    = (const float*)d_in[8];
    const float* bimg    = (const float*)d_in[9];
    const float* Wcls    = (const float*)d_in[10];
    const float* bcls    = (const float*)d_in[11];
    const float* Wml     = (const float*)d_in[12];
    const float* bml     = (const float*)d_in[13];

    float* ws  = (float*)d_ws;
    float* out = (float*)d_out;            // [64,80] then loss at [5120]

    float* feat   = ws + WS_FEAT;
    float* b1     = ws + WS_B1;
    float* b2     = ws + WS_B2;
    float* Aw     = ws + WS_AW;
    float* Ahat   = ws + WS_AHAT;
    float* t1     = ws + WS_T1;
    float* h      = ws + WS_H;
    float* hh     = ws + WS_HH;
    float* x      = ws + WS_X;
    float* img    = ws + WS_IMG;
    float* cls    = ws + WS_CLS;
    float* pooled = ws + WS_POOL;

    fused_init_maxpool<<<36003, 256, 0, stream>>>(feature, feat, x, Aw, t1,
                                                  bimg, img, bcls, cls);
    fused_stage2<<<2420, 256, 0, stream>>>(inp, Wb1, bb1, Wb2, bb2, b1, b2,
                                           Wg1, t1, feat, Wimg, img);
    gram_kernel<<<dim3(25, 8), 256, 0, stream>>>(b1, b2, Aw);
    ahat_kernel<<<1, 256, 0, stream>>>(Aw, Ahat, out + 5120);
    h_kernel<<<320, 256, 0, stream>>>(Ahat, t1, h);
    hh_kernel<<<320, 256, 0, stream>>>(Ahat, h, hh);
    gemm_x_mfma<<<dim3(64, 4), 320, 0, stream>>>(hh, Wg2, x);
    gemm_cls_mfma<<<dim3(125, 4), 320, 0, stream>>>(x, Wcls, cls);
    pool_kernel<<<800, 256, 0, stream>>>(img, cls, pooled);
    out_kernel<<<1280, 256, 0, stream>>>(pooled, Wml, bml, out);
}

// Round 4
// 346.170 us; speedup vs baseline: 1.3008x; 1.0091x over previous
//
#include <hip/hip_runtime.h>
#include <math.h>

// Problem constants
#define B_    64
#define C_    80
#define DE_   300
#define DE1_  1024
#define J_    4000
#define S_    100
#define KP_   40      // J/S
#define FDIM_ 2048

// Workspace layout (float offsets)
#define WS_FEAT   0          // [64,2048]           131072
#define WS_B1     131072     // [1024,80]            81920
#define WS_B2     212992     // [1024,80]            81920
#define WS_AW     294912     // [80,80]               6400
#define WS_AHAT   301312     // [80,80]               6400
#define WS_T1     307712     // [80,1024]            81920
#define WS_H      389632     // [80,1024]            81920
#define WS_HH     471552     // [80,1024]            81920
#define WS_X      553472     // [80,2048]           163840
#define WS_IMG    717312     // [64,4000]           256000
#define WS_CLS    973312     // [80,4000]           320000
#define WS_POOL   1293312    // [64,80,40]          204800

typedef __bf16 bf16x8 __attribute__((ext_vector_type(8)));
typedef float  f32x4  __attribute__((ext_vector_type(4)));

__device__ __forceinline__ bf16x8 cvt_bf16x8(float4 a, float4 b) {
    bf16x8 r;
    r[0] = (__bf16)a.x; r[1] = (__bf16)a.y; r[2] = (__bf16)a.z; r[3] = (__bf16)a.w;
    r[4] = (__bf16)b.x; r[5] = (__bf16)b.y; r[6] = (__bf16)b.z; r[7] = (__bf16)b.w;
    return r;
}

// Explicitly software-pipelined MFMA tile, B^T layout (W row-major [N,K]).
// 16 rows x 32 cols, KSTEPS k-steps of 32. Pointers pre-offset:
// A0 = A+(m0+r)*K+k0+q*8, B0 = W+(n0+r)*K+k0+q*8, B1 = W+(n0+16+r)*K+k0+q*8.
// Depth-4 register pipeline: ~120 VGPRs, 24 float4 loads in flight per wave.
template<int KSTEPS>
__device__ __forceinline__ void mfma_bt_pipe(const float* __restrict__ A0,
                                             const float* __restrict__ B0,
                                             const float* __restrict__ B1,
                                             f32x4& acc0, f32x4& acc1) {
    constexpr int D = 4;
    float4 ra[D][2], rb0[D][2], rb1[D][2];
    #pragma unroll
    for (int p = 0; p < D; ++p) {
        ra[p][0]  = ((const float4*)(A0 + p * 32))[0];
        ra[p][1]  = ((const float4*)(A0 + p * 32))[1];
        rb0[p][0] = ((const float4*)(B0 + p * 32))[0];
        rb0[p][1] = ((const float4*)(B0 + p * 32))[1];
        rb1[p][0] = ((const float4*)(B1 + p * 32))[0];
        rb1[p][1] = ((const float4*)(B1 + p * 32))[1];
    }
    #pragma unroll
    for (int ks = 0; ks < KSTEPS; ++ks) {
        const int slot = ks % D;
        bf16x8 af  = cvt_bf16x8(ra[slot][0],  ra[slot][1]);
        bf16x8 bf0 = cvt_bf16x8(rb0[slot][0], rb0[slot][1]);
        bf16x8 bf1 = cvt_bf16x8(rb1[slot][0], rb1[slot][1]);
        if (ks + D < KSTEPS) {
            ra[slot][0]  = ((const float4*)(A0 + (ks + D) * 32))[0];
            ra[slot][1]  = ((const float4*)(A0 + (ks + D) * 32))[1];
            rb0[slot][0] = ((const float4*)(B0 + (ks + D) * 32))[0];
            rb0[slot][1] = ((const float4*)(B0 + (ks + D) * 32))[1];
            rb1[slot][0] = ((const float4*)(B1 + (ks + D) * 32))[0];
            rb1[slot][1] = ((const float4*)(B1 + (ks + D) * 32))[1];
        }
        acc0 = __builtin_amdgcn_mfma_f32_16x16x32_bf16(af, bf0, acc0, 0, 0, 0);
        acc1 = __builtin_amdgcn_mfma_f32_16x16x32_bf16(af, bf1, acc1, 0, 0, 0);
    }
}

__device__ __forceinline__ void mfma_store_atomic(float* __restrict__ C, int Nst,
                                                  int m0, int n0, int r, int q,
                                                  const f32x4& acc0, const f32x4& acc1) {
    #pragma unroll
    for (int i = 0; i < 4; ++i) {
        int row = m0 + q * 4 + i;
        atomicAdd(&C[(size_t)row * Nst + n0 + r], acc0[i]);
        atomicAdd(&C[(size_t)row * Nst + n0 + 16 + r], acc1[i]);
    }
}

// ================================================================ launch 1
// blocks [0,32768): maxpool.  blocks [32768,36003): init
__global__ void fused_init_maxpool(const float* __restrict__ feature,
                                   float* __restrict__ feat,
                                   float* __restrict__ x, float* __restrict__ Aw,
                                   float* __restrict__ t1,
                                   const float* __restrict__ bimg, float* __restrict__ img,
                                   const float* __restrict__ bcls, float* __restrict__ cls) {
    if (blockIdx.x < 32768) {
        int gtid = blockIdx.x * 256 + threadIdx.x;
        int wid  = gtid >> 6;       // 0..131071
        int lane = gtid & 63;
        const float* src = feature + (size_t)wid * 196;
        float v = -INFINITY;
        if (lane < 49) {
            float4 u = ((const float4*)src)[lane];
            v = fmaxf(fmaxf(u.x, u.y), fmaxf(u.z, u.w));
        }
        #pragma unroll
        for (int off = 32; off > 0; off >>= 1)
            v = fmaxf(v, __shfl_down(v, off));
        if (lane == 0) feat[wid] = v;
        return;
    }
    int idx = (blockIdx.x - 32768) * 256 + threadIdx.x;
    if (idx < 163840) { x[idx] = 0.0f; return; }
    idx -= 163840;
    if (idx < 6400) {
        int i = idx / 80, j = idx % 80;
        Aw[idx] = (i == j) ? 1.0f : 0.0f;
        return;
    }
    idx -= 6400;
    if (idx < 81920) { t1[idx] = 0.0f; return; }
    idx -= 81920;
    if (idx < 256000) { img[idx] = bimg[idx % 4000]; return; }
    idx -= 256000;
    if (idx < 320000) { cls[idx] = bcls[idx % 4000]; }
}

// ================================================================ launch 2
// blocks [0,640): b1b2 | [640,1920): t1 split-K4
__global__ void fused_stage2(const float* __restrict__ inp,
                             const float* __restrict__ Wb1, const float* __restrict__ bb1,
                             const float* __restrict__ Wb2, const float* __restrict__ bb2,
                             float* __restrict__ b1, float* __restrict__ b2,
                             const float* __restrict__ Wg1, float* __restrict__ t1) {
    int bid = blockIdx.x;
    if (bid < 640) {
        int idx = bid * 256 + threadIdx.x;     // 0 .. 163839
        int which = idx >= 81920;
        int r = which ? idx - 81920 : idx;
        int o = r / 80, c = r % 80;
        const float* W = which ? Wb2 : Wb1;
        const float* bb = which ? bb2 : bb1;
        float acc = bb[o];
        const float* wrow = W + o * 300;
        #pragma unroll 10
        for (int k = 0; k < 300; ++k)
            acc = fmaf(wrow[k], inp[k * 80 + c], acc);
        float s = 1.0f / (1.0f + expf(-acc));
        (which ? b2 : b1)[r] = s;
        return;
    }
    // ---- t1 += inp @ Wg1 (split-K 4, chunks of 75)
    int bid2 = bid - 640;
    int chunk = bid2 / 320, blk = bid2 % 320;
    int idx = blk * 256 + threadIdx.x;     // 0..81919
    int m = idx >> 10, n = idx & 1023;
    float acc = 0.f;
    const float* arow = inp + m * 300;
    int k0 = chunk * 75;
    #pragma unroll 5
    for (int k = k0; k < k0 + 75; ++k)
        acc = fmaf(arow[k], Wg1[k * 1024 + n], acc);
    atomicAdd(&t1[idx], acc);
}

// ================================================================ launch 3
// blocks [0,200): gram split-K8 | [200,1200): img MFMA split-K8 (pipelined)
__global__ void fused_stage3(const float* __restrict__ b1, const float* __restrict__ b2,
                             float* __restrict__ Aw,
                             const float* __restrict__ feat, const float* __restrict__ Wimg,
                             float* __restrict__ img) {
    int bid = blockIdx.x;
    if (bid < 200) {
        int idx = (bid % 25) * 256 + threadIdx.x;   // 0..6399
        int i = idx / 80, j = idx % 80;
        int k0 = (bid / 25) * 128;
        float acc = 0.f;
        #pragma unroll 8
        for (int k = k0; k < k0 + 128; ++k)
            acc = fmaf(b1[k * 80 + i], b2[k * 80 + j], acc);
        atomicAdd(&Aw[idx], acc * (1.0f / 80.0f));
        return;
    }
    // ---- img += feat @ Wimg^T : M=64 (4 waves x 16 rows), n-tile 32, k-chunk 256
    int bid3 = bid - 200;                     // 0..999
    int nt = bid3 % 125, kc = bid3 / 125;
    int w = threadIdx.x >> 6;
    int lane = threadIdx.x & 63;
    int r = lane & 15, q = lane >> 4;
    int n0 = nt * 32, m0 = w * 16, k0 = kc * 256;
    const float* A0 = feat + (size_t)(m0 + r) * 2048 + k0 + q * 8;
    const float* B0 = Wimg + (size_t)(n0 + r) * 2048 + k0 + q * 8;
    const float* B1 = Wimg + (size_t)(n0 + 16 + r) * 2048 + k0 + q * 8;
    f32x4 acc0 = {0.f, 0.f, 0.f, 0.f}, acc1 = {0.f, 0.f, 0.f, 0.f};
    mfma_bt_pipe<8>(A0, B0, B1, acc0, acc1);
    mfma_store_atomic(img, 4000, m0, n0, r, q, acc0, acc1);
}

// ---------------------------------------------------------------- A_hat + loss
__global__ void ahat_kernel(const float* __restrict__ Aw,
                            float* __restrict__ Ahat,
                            float* __restrict__ loss_out) {
    __shared__ float rs[80];
    __shared__ float dsh[80];
    __shared__ float red[256];
    int tid = threadIdx.x;
    if (tid < 80) rs[tid] = 0.f;
    __syncthreads();
    for (int idx = tid; idx < 6400; idx += 256)
        atomicAdd(&rs[idx / 80], Aw[idx]);
    __syncthreads();
    if (tid < 80) {
        float dv = rsqrtf(rs[tid]);
        if (!isfinite(dv)) dv = 0.f;
        dsh[tid] = dv;
    }
    __syncthreads();
    float loss = 0.f;
    for (int idx = tid; idx < 6400; idx += 256) {
        int i = idx / 80, j = idx % 80;
        float ah = dsh[i] * Aw[idx] * dsh[j];
        Ahat[idx] = ah;
        loss += fabsf(ah - (i == j ? 1.0f : 0.0f));
    }
    red[tid] = loss;
    __syncthreads();
    for (int s = 128; s > 0; s >>= 1) {
        if (tid < s) red[tid] += red[tid + s];
        __syncthreads();
    }
    if (tid == 0) *loss_out = red[0];
}

// ---------------------------------------------------------------- h = leaky(Ahat @ t1)
__global__ void h_kernel(const float* __restrict__ Ahat,
                         const float* __restrict__ t1,
                         float* __restrict__ h) {
    int idx = blockIdx.x * 256 + threadIdx.x;
    int m = idx >> 10, n = idx & 1023;
    float acc = 0.f;
    const float* arow = Ahat + m * 80;
    #pragma unroll 8
    for (int k = 0; k < 80; ++k)
        acc = fmaf(arow[k], t1[k * 1024 + n], acc);
    h[idx] = acc > 0.f ? acc : 0.2f * acc;
}

// ---------------------------------------------------------------- hh = Ahat @ h
__global__ void hh_kernel(const float* __restrict__ Ahat,
                          const float* __restrict__ h,
                          float* __restrict__ hh) {
    int idx = blockIdx.x * 256 + threadIdx.x;
    int m = idx >> 10, n = idx & 1023;
    float acc = 0.f;
    const float* arow = Ahat + m * 80;
    #pragma unroll 8
    for (int k = 0; k < 80; ++k)
        acc = fmaf(arow[k], h[k * 1024 + n], acc);
    hh[idx] = acc;
}

// ---------------------------------------------------------------- x += hh @ Wg2 (MFMA, split-K 4, pipelined)
// Wg2 row-major [K=1024, N=2048]: B loads are per-lane scalar column reads.
__global__ __launch_bounds__(320) void gemm_x_mfma(const float* __restrict__ hh,
                                                   const float* __restrict__ Wg2,
                                                   float* __restrict__ x) {
    int w = threadIdx.x >> 6;
    int lane = threadIdx.x & 63;
    int r = lane & 15, q = lane >> 4;
    int n0 = blockIdx.x * 32;
    int k0 = blockIdx.y * 256;
    int m0 = w * 16;

    const float* arow = hh + (size_t)(m0 + r) * 1024 + k0 + q * 8;
    const float* bcol = Wg2 + (size_t)(k0 + q * 8) * 2048 + n0 + r;

    constexpr int D = 4, KS = 8;
    float4 ra[D][2];
    float rb0[D][8], rb1[D][8];
    #pragma unroll
    for (int p = 0; p < D; ++p) {
        ra[p][0] = ((const float4*)(arow + p * 32))[0];
        ra[p][1] = ((const float4*)(arow + p * 32))[1];
        const float* bp = bcol + (size_t)p * 32 * 2048;
        #pragma unroll
        for (int j = 0; j < 8; ++j) {
            rb0[p][j] = bp[(size_t)j * 2048];
            rb1[p][j] = bp[(size_t)j * 2048 + 16];
        }
    }
    f32x4 acc0 = {0.f, 0.f, 0.f, 0.f}, acc1 = {0.f, 0.f, 0.f, 0.f};
    #pragma unroll
    for (int ks = 0; ks < KS; ++ks) {
        const int slot = ks % D;
        bf16x8 af = cvt_bf16x8(ra[slot][0], ra[slot][1]);
        bf16x8 bf0, bf1;
        #pragma unroll
        for (int j = 0; j < 8; ++j) {
            bf0[j] = (__bf16)rb0[slot][j];
            bf1[j] = (__bf16)rb1[slot][j];
        }
        if (ks + D < KS) {
            ra[slot][0] = ((const float4*)(arow + (ks + D) * 32))[0];
            ra[slot][1] = ((const float4*)(arow + (ks + D) * 32))[1];
            const float* bp = bcol + (size_t)(ks + D) * 32 * 2048;
            #pragma unroll
            for (int j = 0; j < 8; ++j) {
                rb0[slot][j] = bp[(size_t)j * 2048];
                rb1[slot][j] = bp[(size_t)j * 2048 + 16];
            }
        }
        acc0 = __builtin_amdgcn_mfma_f32_16x16x32_bf16(af, bf0, acc0, 0, 0, 0);
        acc1 = __builtin_amdgcn_mfma_f32_16x16x32_bf16(af, bf1, acc1, 0, 0, 0);
    }
    mfma_store_atomic(x, 2048, m0, n0, r, q, acc0, acc1);
}

// ---------------------------------------------------------------- cls += x @ Wcls^T (MFMA, split-K 8, pipelined)
__global__ __launch_bounds__(320) void gemm_cls_mfma(const float* __restrict__ x,
                                                     const float* __restrict__ Wcls,
                                                     float* __restrict__ cls) {
    int w = threadIdx.x >> 6;
    int lane = threadIdx.x & 63;
    int r = lane & 15, q = lane >> 4;
    int n0 = blockIdx.x * 32;
    int k0 = blockIdx.y * 256;
    int m0 = w * 16;
    const float* A0 = x    + (size_t)(m0 + r) * 2048 + k0 + q * 8;
    const float* B0 = Wcls + (size_t)(n0 + r) * 2048 + k0 + q * 8;
    const float* B1 = Wcls + (size_t)(n0 + 16 + r) * 2048 + k0 + q * 8;
    f32x4 acc0 = {0.f, 0.f, 0.f, 0.f}, acc1 = {0.f, 0.f, 0.f, 0.f};
    mfma_bt_pipe<8>(A0, B0, B1, acc0, acc1);
    mfma_store_atomic(cls, 4000, m0, n0, r, q, acc0, acc1);
}

// ---------------------------------------------------------------- MFB pooled
__global__ void pool_kernel(const float* __restrict__ img,
                            const float* __restrict__ cls,
                            float* __restrict__ pooled) {
    int idx = blockIdx.x * 256 + threadIdx.x;     // 0..204799
    int b = idx / 3200;
    int rem = idx % 3200;
    int c = rem / 40, k = rem % 40;
    const float4* ia = (const float4*)(img + (size_t)b * 4000 + k * 100);
    const float4* ca = (const float4*)(cls + (size_t)c * 4000 + k * 100);
    float acc = 0.f;
    #pragma unroll 5
    for (int s = 0; s < 25; ++s) {
        float4 u = ia[s], v = ca[s];
        acc = fmaf(u.x, v.x, acc);
        acc = fmaf(u.y, v.y, acc);
        acc = fmaf(u.z, v.z, acc);
        acc = fmaf(u.w, v.w, acc);
    }
    pooled[(size_t)b * 3200 + c * 40 + k] = acc;
}

// ---------------------------------------------------------------- out: one wave per output
__global__ void out_kernel(const float* __restrict__ pooled,
                           const float* __restrict__ Wml,
                           const float* __restrict__ bml,
                           float* __restrict__ out) {
    int gid = blockIdx.x * 256 + threadIdx.x;
    int wid = gid >> 6;       // 0..5119
    int lane = gid & 63;
    int b = wid / 80, co = wid % 80;
    const float* pr = pooled + (size_t)b * 3200;
    const float* wr = Wml + (size_t)co * 3200;
    float acc = 0.f;
    #pragma unroll 5
    for (int k = lane; k < 3200; k += 64)
        acc = fmaf(pr[k], wr[k], acc);
    #pragma unroll
    for (int off = 32; off > 0; off >>= 1)
        acc += __shfl_down(acc, off);
    if (lane == 0) out[wid] = acc + bml[co];
}

// ---------------------------------------------------------------- launch
extern "C" void kernel_launch(void* const* d_in, const int* in_sizes, int n_in,
                              void* d_out, int out_size, void* d_ws, size_t ws_size,
                              hipStream_t stream) {
    const float* feature = (const float*)d_in[0];
    const float* inp     = (const float*)d_in[1];
    const float* Wb1     = (const float*)d_in[2];
    const float* bb1     = (const float*)d_in[3];
    const float* Wb2     = (const float*)d_in[4];
    const float* bb2     = (const float*)d_in[5];
    const float* Wg1     = (const float*)d_in[6];
    const float* Wg2     = (const float*)d_in[7];
    const float* Wimg    = (const float*)d_in[8];
    const float* bimg    = (const float*)d_in[9];
    const float* Wcls    = (const float*)d_in[10];
    const float* bcls    = (const float*)d_in[11];
    const float* Wml     = (const float*)d_in[12];
    const float* bml     = (const float*)d_in[13];

    float* ws  = (float*)d_ws;
    float* out = (float*)d_out;            // [64,80] then loss at [5120]

    float* feat   = ws + WS_FEAT;
    float* b1     = ws + WS_B1;
    float* b2     = ws + WS_B2;
    float* Aw     = ws + WS_AW;
    float* Ahat   = ws + WS_AHAT;
    float* t1     = ws + WS_T1;
    float* h      = ws + WS_H;
    float* hh     = ws + WS_HH;
    float* x      = ws + WS_X;
    float* img    = ws + WS_IMG;
    float* cls    = ws + WS_CLS;
    float* pooled = ws + WS_POOL;

    fused_init_maxpool<<<36003, 256, 0, stream>>>(feature, feat, x, Aw, t1,
                                                  bimg, img, bcls, cls);
    fused_stage2<<<1920, 256, 0, stream>>>(inp, Wb1, bb1, Wb2, bb2, b1, b2, Wg1, t1);
    fused_stage3<<<1200, 256, 0, stream>>>(b1, b2, Aw, feat, Wimg, img);
    ahat_kernel<<<1, 256, 0, stream>>>(Aw, Ahat, out + 5120);
    h_kernel<<<320, 256, 0, stream>>>(Ahat, t1, h);
    hh_kernel<<<320, 256, 0, stream>>>(Ahat, h, hh);
    gemm_x_mfma<<<dim3(64, 4), 320, 0, stream>>>(hh, Wg2, x);
    gemm_cls_mfma<<<dim3(125, 8), 320, 0, stream>>>(x, Wcls, cls);
    pool_kernel<<<800, 256, 0, stream>>>(img, cls, pooled);
    out_kernel<<<1280, 256, 0, stream>>>(pooled, Wml, bml, out);
}